// Round 4
// baseline (250.092 us; speedup 1.0000x reference)
//
#include <hip/hip_runtime.h>

#define HW 64
#define CIN 256
#define OC1 128
#define NJ 49
#define KZ 8          // K-split: each conv1 block does 32 ic x 49 taps
#define XW 20         // LDS words per (row,col) ic-group (40 shorts = 32 ic + 8 pad)
#define COLS 80
#define BUFW (2 * COLS * XW)   // 3200 words per LDS buffer

typedef short bf16x8 __attribute__((ext_vector_type(8)));
typedef float f32x4 __attribute__((ext_vector_type(4)));

__device__ __forceinline__ unsigned f2bf_pack(float a, float b) {
    unsigned ua = __float_as_uint(a);
    ua += 0x7FFF + ((ua >> 16) & 1);
    unsigned ub = __float_as_uint(b);
    ub += 0x7FFF + ((ub >> 16) & 1);
    return (ua >> 16) | (ub & 0xFFFF0000u);
}

__device__ __forceinline__ unsigned short f2bf(float a) {
    unsigned u = __float_as_uint(a);
    u += 0x7FFF + ((u >> 16) & 1);
    return (unsigned short)(u >> 16);
}

// ---------------------------------------------------------------------------
// w1 fp32 [128 oc][256 ic][49 tap] -> w1t bf16 [49][128 oc][256 ic]
// ---------------------------------------------------------------------------
__global__ __launch_bounds__(64) void wtrans_kernel(const float* __restrict__ w1,
                                                    unsigned short* __restrict__ w1t) {
    int oc = blockIdx.x >> 2, icq = blockIdx.x & 3;
    int ic = icq * 64 + threadIdx.x;
    const float* src = w1 + ((size_t)oc * 256 + ic) * 49;
    #pragma unroll
    for (int tap = 0; tap < 49; ++tap)
        w1t[((size_t)tap * 128 + oc) * 256 + ic] = f2bf(src[tap]);
}

// ---------------------------------------------------------------------------
// conv1 implicit GEMM, bf16 MFMA 16x16x32, K-split 8, double-buffered LDS.
// grid (8 kz, 32 hp, 4 b) = 1024 blocks; block 256 = 4 waves.
// Block: 128 oc x 128 px (2 rows); wave 64 oc x 64 px; 1 barrier per u.
// P bf16 [kz][b][oc][h][w] partials.
// ---------------------------------------------------------------------------
__global__ __launch_bounds__(256) void conv1_mfma_kernel(
    const float* __restrict__ x, const unsigned short* __restrict__ w1t,
    unsigned short* __restrict__ P)
{
    __shared__ unsigned xs32[2 * BUFW];   // 25.6 KB: [buf][row 2][col 80][icpack 20w]

    const int kz = blockIdx.x, hp = blockIdx.y, b = blockIdx.z;
    const int h0 = hp * 2;
    const int t = threadIdx.x;
    const int lane = t & 63, wv = t >> 6;
    const int oc_off = (wv & 1) * 64;
    const int ri = wv >> 1;               // wave-uniform pixel row (0/1)
    const int l15 = lane & 15, quad = lane >> 4;

    f32x4 acc[4][4];
    #pragma unroll
    for (int i = 0; i < 4; ++i)
        #pragma unroll
        for (int j = 0; j < 4; ++j) acc[i][j] = (f32x4){0.f, 0.f, 0.f, 0.f};

    const float* xb = x + ((size_t)b * CIN + kz * 32) * 4096;
    const unsigned short* wbase = w1t + (size_t)(oc_off + l15) * 256 + kz * 32 + quad * 8;

    // stage rows {h0, h0+1} + 2u - 6, 32 ic, cols -8..71 (stored col = src+8)
    auto stage = [&](int u, int bufw) {
        for (int f = t; f < 640; f += 256) {
            int row = f / 320, rem = f - row * 320;
            int icp = rem / 20, c4 = rem - icp * 20;
            int r = h0 + row + 2 * u - 6;
            float4 g0 = make_float4(0.f, 0.f, 0.f, 0.f), g1 = g0;
            if ((unsigned)r < 64u && (unsigned)(c4 - 2) <= 15u) {
                const float* p = xb + (size_t)(2 * icp) * 4096 + r * 64 + 4 * c4 - 8;
                g0 = *(const float4*)p;
                g1 = *(const float4*)(p + 4096);
            }
            unsigned* dst = &xs32[bufw + (row * COLS + 4 * c4) * XW + icp];
            dst[0]      = f2bf_pack(g0.x, g1.x);
            dst[XW]     = f2bf_pack(g0.y, g1.y);
            dst[2 * XW] = f2bf_pack(g0.z, g1.z);
            dst[3 * XW] = f2bf_pack(g0.w, g1.w);
        }
    };

    stage(0, 0);
    __syncthreads();

    for (int u = 0; u < 7; ++u) {
        const int cur = (u & 1) * BUFW;
        if (u < 6) stage(u + 1, ((u + 1) & 1) * BUFW);   // overlaps taps below

        #pragma unroll
        for (int v = 0; v < 7; ++v) {
            const unsigned short* wp = wbase + (size_t)(u * 7 + v) * (128 * 256);
            bf16x8 wf[4];
            #pragma unroll
            for (int of = 0; of < 4; ++of)
                wf[of] = *(const bf16x8*)(wp + of * (16 * 256));
            #pragma unroll
            for (int pf = 0; pf < 4; ++pf) {
                const int scol = pf * 16 + l15 + 2 * v + 2;
                bf16x8 xf = *(const bf16x8*)((const unsigned short*)xs32
                              + 2 * cur + (ri * COLS + scol) * 40 + 8 * quad);
                #pragma unroll
                for (int of = 0; of < 4; ++of)
                    acc[of][pf] = __builtin_amdgcn_mfma_f32_16x16x32_bf16(
                        wf[of], xf, acc[of][pf], 0, 0, 0);
            }
        }
        __syncthreads();
    }

    // epilogue: D row = oc (quad*4+reg), col = px (l15); store bf16 partials
    unsigned short* Pb = P + (size_t)(kz * 4 + b) * (128 * 4096) + (size_t)(h0 + ri) * 64;
    #pragma unroll
    for (int of = 0; of < 4; ++of) {
        const int oc = oc_off + of * 16 + quad * 4;
        #pragma unroll
        for (int pf = 0; pf < 4; ++pf) {
            const int w = pf * 16 + l15;
            #pragma unroll
            for (int reg = 0; reg < 4; ++reg)
                Pb[(size_t)(oc + reg) * 4096 + w] = f2bf(acc[of][pf][reg]);
        }
    }
}

// ---------------------------------------------------------------------------
// conv2 (1x1, 128->49) + b2 + softmax; reduces 8 bf16 partials + b1.
// grid (64 h, 4 b); block 512. k1s[w][140] transposed, j register-tiled (7/thr).
// ---------------------------------------------------------------------------
__global__ __launch_bounds__(512) void conv2_softmax_kernel(
    const unsigned short* __restrict__ P, const float* __restrict__ w2,
    const float* __restrict__ b2, const float* __restrict__ b1,
    float* __restrict__ attn)
{
    __shared__ float k1s[64 * 140];   // [w][oc] pad 140 -> b128 reads conflict-free
    __shared__ float k2s[64 * 56];    // [w][j]  pad 56
    const int h = blockIdx.x, b = blockIdx.y;
    const int t = threadIdx.x;

    for (int f = t; f < OC1 * 64; f += 512) {
        int w = f & 63, oc = f >> 6;
        float s = b1[oc];
        #pragma unroll
        for (int kzi = 0; kzi < KZ; ++kzi) {
            unsigned u = P[(((size_t)(kzi * 4 + b) * 128 + oc) * 64 + h) * 64 + w];
            s += __uint_as_float(u << 16);
        }
        k1s[w * 140 + oc] = s;
    }
    __syncthreads();

    const int w = t & 63, jg = t >> 6;   // jg 0..7, wave-uniform
    float acc[7];
    if (jg < 7) {                        // j = 7*jg + jj covers 0..48
        #pragma unroll
        for (int jj = 0; jj < 7; ++jj) acc[jj] = b2[7 * jg + jj];
        const float4* kv = (const float4*)&k1s[w * 140];
        for (int oc4 = 0; oc4 < 32; ++oc4) {
            float4 v = kv[oc4];
            #pragma unroll
            for (int jj = 0; jj < 7; ++jj) {
                const float* wr = w2 + (size_t)(7 * jg + jj) * OC1 + 4 * oc4;
                acc[jj] += v.x * wr[0] + v.y * wr[1] + v.z * wr[2] + v.w * wr[3];
            }
        }
        #pragma unroll
        for (int jj = 0; jj < 7; ++jj) k2s[w * 56 + 7 * jg + jj] = acc[jj];
    } else {
        #pragma unroll
        for (int j = 49; j < 56; ++j) k2s[w * 56 + j] = -1e30f;   // pad
    }
    __syncthreads();

    // softmax over j per pixel w (redundant per jg; values held in regs)
    float4 vv[13];                         // j 0..51 (49..51 are -1e30 pad)
    const float4* k2v = (const float4*)&k2s[w * 56];
    float m = -1e30f;
    #pragma unroll
    for (int i = 0; i < 13; ++i) {
        vv[i] = k2v[i];
        m = fmaxf(m, fmaxf(fmaxf(vv[i].x, vv[i].y), fmaxf(vv[i].z, vv[i].w)));
    }
    float s = 0.f;
    #pragma unroll
    for (int i = 0; i < 13; ++i) {
        s += __expf(vv[i].x - m) + __expf(vv[i].y - m)
           + __expf(vv[i].z - m) + __expf(vv[i].w - m);
    }
    const float inv = 1.f / s;

    if (jg < 7) {
        float* ab = attn + ((size_t)b * NJ * 4096) + (size_t)h * 64 + w;
        #pragma unroll
        for (int jj = 0; jj < 7; ++jj)
            ab[(size_t)(7 * jg + jj) * 4096] = __expf(acc[jj] - m) * inv;
    }
}

// ---------------------------------------------------------------------------
// gather: out[b,c,h,w] = sum_{u,v} attn[b,u*7+v,h,w] * x[b,c,h+2u-6,w+2v-6]
// ---------------------------------------------------------------------------
__global__ __launch_bounds__(256) void gather_kernel(
    const float* __restrict__ x, const float* __restrict__ attn,
    float* __restrict__ out)
{
    __shared__ float as[NJ * 64];
    const int cg = blockIdx.x, h = blockIdx.y, b = blockIdx.z;
    const int t = threadIdx.x;

    const float* ab = attn + ((size_t)(b * NJ) * HW + h) * HW;
    for (int f = t; f < NJ * 64; f += 256)
        as[f] = ab[(f >> 6) * 4096 + (f & 63)];
    __syncthreads();

    const int w = t & 63, cs = t >> 6;
    const int c0 = cg * 32 + cs * 8;
    const float* xb = x + (size_t)(b * CIN + c0) * 4096;

    float acc[8];
    #pragma unroll
    for (int i = 0; i < 8; ++i) acc[i] = 0.f;

    #pragma unroll
    for (int u = 0; u < 7; ++u) {
        const int row = h + 2 * u - 6;
        if ((unsigned)row >= 64u) continue;
        #pragma unroll
        for (int v = 0; v < 7; ++v) {
            const int col = w + 2 * v - 6;
            const float a = as[(u * 7 + v) * 64 + w];
            if ((unsigned)col < 64u) {
                #pragma unroll
                for (int i = 0; i < 8; ++i)
                    acc[i] += a * xb[i * 4096 + row * 64 + col];
            }
        }
    }

    float* ob = out + (size_t)(b * CIN + c0) * 4096 + h * 64;
    #pragma unroll
    for (int i = 0; i < 8; ++i) ob[i * 4096 + w] = acc[i];
}

// ---------------------------------------------------------------------------
// ws: w1t bf16 3,211,264 B | P bf16 [8][4][128][4096] = 33,554,432 B |
//     attn fp32 3,211,264 B   (~40 MB total)
// ---------------------------------------------------------------------------
extern "C" void kernel_launch(void* const* d_in, const int* in_sizes, int n_in,
                              void* d_out, int out_size, void* d_ws, size_t ws_size,
                              hipStream_t stream) {
    const float* x  = (const float*)d_in[0];
    const float* w1 = (const float*)d_in[1];
    const float* b1 = (const float*)d_in[2];
    const float* w2 = (const float*)d_in[3];
    const float* b2 = (const float*)d_in[4];
    float* out = (float*)d_out;

    unsigned short* w1t = (unsigned short*)d_ws;
    unsigned short* P   = (unsigned short*)((char*)d_ws + 3211264);
    float* attn         = (float*)((char*)d_ws + 3211264 + 33554432);

    wtrans_kernel<<<512, 64, 0, stream>>>(w1, w1t);
    conv1_mfma_kernel<<<dim3(KZ, 32, 4), 256, 0, stream>>>(x, w1t, P);
    conv2_softmax_kernel<<<dim3(HW, 4), 512, 0, stream>>>(P, w2, b2, b1, attn);
    gather_kernel<<<dim3(8, HW, 4), 256, 0, stream>>>(x, attn, out);
}

// Round 5
// 240.212 us; speedup vs baseline: 1.0411x; 1.0411x over previous
//
#include <hip/hip_runtime.h>

#define HW 64
#define CIN 256
#define OC1 128
#define NJ 49
#define KZ 4            // K-split: each conv1 block does 64 ic x 49 taps
#define CELLW 36        // words per (row,col) cell: 32 ic-pair words + 4 pad
#define BUFW (2 * 80 * CELLW)   // 5760 words = 23,040 B per buffer

typedef short bf16x8 __attribute__((ext_vector_type(8)));
typedef float f32x4 __attribute__((ext_vector_type(4)));

__device__ __forceinline__ unsigned f2bf_pack(float a, float b) {
    unsigned ua = __float_as_uint(a);
    ua += 0x7FFF + ((ua >> 16) & 1);
    unsigned ub = __float_as_uint(b);
    ub += 0x7FFF + ((ub >> 16) & 1);
    return (ua >> 16) | (ub & 0xFFFF0000u);
}

__device__ __forceinline__ unsigned short f2bf(float a) {
    unsigned u = __float_as_uint(a);
    u += 0x7FFF + ((u >> 16) & 1);
    return (unsigned short)(u >> 16);
}

// ---------------------------------------------------------------------------
// w1 fp32 [128 oc][256 ic][49 tap] -> w1t bf16 [49][128 oc][256 ic]
// 128 blocks (one oc each): coalesced float4 read -> LDS -> coalesced write.
// ---------------------------------------------------------------------------
__global__ __launch_bounds__(256) void wtrans_kernel(const float* __restrict__ w1,
                                                     unsigned short* __restrict__ w1t) {
    __shared__ float ws[12544];     // [ic 256][tap 49], 50 KB
    const int oc = blockIdx.x;
    const float4* src = (const float4*)(w1 + (size_t)oc * 12544);
    for (int f = threadIdx.x; f < 3136; f += 256)
        *(float4*)&ws[4 * f] = src[f];
    __syncthreads();
    for (int k = threadIdx.x; k < 12544; k += 256) {
        int tap = k >> 8, ic = k & 255;   // stride 49 mod 32 = 17: conflict-free
        w1t[((size_t)tap * 128 + oc) * 256 + ic] = f2bf(ws[ic * 49 + tap]);
    }
}

// ---------------------------------------------------------------------------
// conv1 implicit GEMM, bf16 MFMA 16x16x32, KZ=4, dbuf LDS, wf software pipeline.
// grid (4 kz, 32 hp, 4 b) = 512 blocks; block 256 = 4 waves (2 oc x 2 px-rows).
// P bf16 [kz][b][oc][h][w] partials.
// ---------------------------------------------------------------------------
__global__ __launch_bounds__(256) void conv1_mfma_kernel(
    const float* __restrict__ x, const unsigned short* __restrict__ w1t,
    unsigned short* __restrict__ P)
{
    __shared__ unsigned xs[2 * BUFW];   // 46,080 B

    const int kz = blockIdx.x, hp = blockIdx.y, b = blockIdx.z;
    const int h0 = hp * 2;
    const int t = threadIdx.x;
    const int lane = t & 63, wv = t >> 6;
    const int oc_off = (wv & 1) * 64;
    const int ri = wv >> 1;             // wave-uniform pixel row (0/1)
    const int l15 = lane & 15, quad = lane >> 4;

    f32x4 acc[4][4];
    #pragma unroll
    for (int i = 0; i < 4; ++i)
        #pragma unroll
        for (int j = 0; j < 4; ++j) acc[i][j] = (f32x4){0.f, 0.f, 0.f, 0.f};

    const float* xb = x + ((size_t)b * CIN + kz * 64) * 4096;
    const unsigned short* wbase = w1t + (size_t)(oc_off + l15) * 256 + kz * 64 + quad * 8;

    // staging decode: f in [0,2560) -> (row, icq 16, col 80); 10 slots/thread.
    int s_row[10], s_icq[10], s_col[10];
    #pragma unroll
    for (int i = 0; i < 10; ++i) {
        int f = t + i * 256;
        int row = f / 1280, rem = f - row * 1280;
        int icq = rem / 80;
        s_row[i] = row; s_icq[i] = icq; s_col[i] = rem - icq * 80;
    }

    // loads coalesced over col; LDS write = single b64 at lane-stride 36 words.
    auto stage = [&](int u, unsigned* buf) {
        #pragma unroll
        for (int i = 0; i < 10; ++i) {
            int r = h0 + s_row[i] + 2 * u - 6;
            int c = s_col[i] - 8;
            float v0 = 0.f, v1 = 0.f, v2 = 0.f, v3 = 0.f;
            if ((unsigned)r < 64u && (unsigned)c < 64u) {
                const float* p = xb + (size_t)(4 * s_icq[i]) * 4096 + r * 64 + c;
                v0 = p[0]; v1 = p[4096]; v2 = p[8192]; v3 = p[12288];
            }
            uint2 pk = make_uint2(f2bf_pack(v0, v1), f2bf_pack(v2, v3));
            *(uint2*)&buf[(s_row[i] * 80 + s_col[i]) * CELLW + 2 * s_icq[i]] = pk;
        }
    };

    bf16x8 wfA[4], wfB[4];
    auto ldwf = [&](int s, bf16x8* d) {
        int tap = s >> 1, ks = s & 1;
        const unsigned short* wp = wbase + (size_t)tap * (128 * 256) + ks * 32;
        #pragma unroll
        for (int of = 0; of < 4; ++of)
            d[of] = *(const bf16x8*)(wp + of * (16 * 256));
    };

    stage(0, xs);
    ldwf(0, wfA);
    __syncthreads();

    for (int u = 0; u < 7; ++u) {
        unsigned* cur = &xs[(u & 1) * BUFW];
        if (u < 6) stage(u + 1, &xs[((u + 1) & 1) * BUFW]);

        #pragma unroll
        for (int v = 0; v < 7; ++v) {
            #pragma unroll
            for (int ks = 0; ks < 2; ++ks) {
                const int s = (u * 7 + v) * 2 + ks;
                const int sp = (s < 97) ? s + 1 : 97;       // prefetch next K-step
                if (s & 1) ldwf(sp, wfA); else ldwf(sp, wfB);
                const bf16x8* cw = (s & 1) ? wfB : wfA;

                const unsigned short* xp = (const unsigned short*)cur
                                           + ks * 32 + quad * 8;
                bf16x8 xf[4];
                #pragma unroll
                for (int pf = 0; pf < 4; ++pf) {
                    const int scol = pf * 16 + l15 + 2 * v + 2;
                    xf[pf] = *(const bf16x8*)(xp + (ri * 80 + scol) * (2 * CELLW));
                }
                #pragma unroll
                for (int of = 0; of < 4; ++of)
                    #pragma unroll
                    for (int pf = 0; pf < 4; ++pf)
                        acc[of][pf] = __builtin_amdgcn_mfma_f32_16x16x32_bf16(
                            cw[of], xf[pf], acc[of][pf], 0, 0, 0);
            }
        }
        __syncthreads();
    }

    unsigned short* Pb = P + (size_t)(kz * 4 + b) * (128 * 4096) + (size_t)(h0 + ri) * 64;
    #pragma unroll
    for (int of = 0; of < 4; ++of) {
        const int oc = oc_off + of * 16 + quad * 4;
        #pragma unroll
        for (int pf = 0; pf < 4; ++pf) {
            const int w = pf * 16 + l15;
            #pragma unroll
            for (int reg = 0; reg < 4; ++reg)
                Pb[(size_t)(oc + reg) * 4096 + w] = f2bf(acc[of][pf][reg]);
        }
    }
}

// ---------------------------------------------------------------------------
// conv2 (1x1, 128->49) + b2 + softmax; reduces KZ bf16 partials + b1.
// grid (64 h, 4 b); block 512. k1s[w][140] transposed, j register-tiled.
// ---------------------------------------------------------------------------
__global__ __launch_bounds__(512) void conv2_softmax_kernel(
    const unsigned short* __restrict__ P, const float* __restrict__ w2,
    const float* __restrict__ b2, const float* __restrict__ b1,
    float* __restrict__ attn)
{
    __shared__ float k1s[64 * 140];
    __shared__ float k2s[64 * 56];
    const int h = blockIdx.x, b = blockIdx.y;
    const int t = threadIdx.x;

    for (int f = t; f < OC1 * 64; f += 512) {
        int w = f & 63, oc = f >> 6;
        float s = b1[oc];
        #pragma unroll
        for (int kzi = 0; kzi < KZ; ++kzi) {
            unsigned u = P[(((size_t)(kzi * 4 + b) * 128 + oc) * 64 + h) * 64 + w];
            s += __uint_as_float(u << 16);
        }
        k1s[w * 140 + oc] = s;
    }
    __syncthreads();

    const int w = t & 63, jg = t >> 6;
    float acc[7];
    if (jg < 7) {
        #pragma unroll
        for (int jj = 0; jj < 7; ++jj) acc[jj] = b2[7 * jg + jj];
        const float4* kv = (const float4*)&k1s[w * 140];
        for (int oc4 = 0; oc4 < 32; ++oc4) {
            float4 v = kv[oc4];
            #pragma unroll
            for (int jj = 0; jj < 7; ++jj) {
                const float* wr = w2 + (size_t)(7 * jg + jj) * OC1 + 4 * oc4;
                acc[jj] += v.x * wr[0] + v.y * wr[1] + v.z * wr[2] + v.w * wr[3];
            }
        }
        #pragma unroll
        for (int jj = 0; jj < 7; ++jj) k2s[w * 56 + 7 * jg + jj] = acc[jj];
    } else {
        #pragma unroll
        for (int j = 49; j < 56; ++j) k2s[w * 56 + j] = -1e30f;
    }
    __syncthreads();

    float4 vv[13];
    const float4* k2v = (const float4*)&k2s[w * 56];
    float m = -1e30f;
    #pragma unroll
    for (int i = 0; i < 13; ++i) {
        vv[i] = k2v[i];
        m = fmaxf(m, fmaxf(fmaxf(vv[i].x, vv[i].y), fmaxf(vv[i].z, vv[i].w)));
    }
    float s = 0.f;
    #pragma unroll
    for (int i = 0; i < 13; ++i) {
        s += __expf(vv[i].x - m) + __expf(vv[i].y - m)
           + __expf(vv[i].z - m) + __expf(vv[i].w - m);
    }
    const float inv = 1.f / s;

    if (jg < 7) {
        float* ab = attn + ((size_t)b * NJ * 4096) + (size_t)h * 64 + w;
        #pragma unroll
        for (int jj = 0; jj < 7; ++jj)
            ab[(size_t)(7 * jg + jj) * 4096] = __expf(acc[jj] - m) * inv;
    }
}

// ---------------------------------------------------------------------------
// gather: out[b,c,h,w] = sum_{u,v} attn[b,u*7+v,h,w] * x[b,c,h+2u-6,w+2v-6]
// grid (8 cg, 64 h, 4 b); block 256. Thread = 4 w x 2 ch; float4 x loads
// reused across the 7 v-taps; float4 LDS attn reads.
// ---------------------------------------------------------------------------
__global__ __launch_bounds__(256) void gather_kernel(
    const float* __restrict__ x, const float* __restrict__ attn,
    float* __restrict__ out)
{
    __shared__ float as[NJ * 64];
    const int cg = blockIdx.x, h = blockIdx.y, b = blockIdx.z;
    const int t = threadIdx.x;

    const float* ab = attn + ((size_t)(b * NJ) * HW + h) * HW;
    for (int f = t; f < NJ * 64; f += 256)
        as[f] = ab[(f >> 6) * 4096 + (f & 63)];
    __syncthreads();

    const int wp = t & 15, cs = t >> 4;   // 16 w-quads x 16 ch-pairs
    const int w0 = wp * 4;
    const int c0 = cg * 32 + cs * 2;
    const float* xb = x + (size_t)(b * CIN + c0) * 4096;

    float acc[2][4];
    #pragma unroll
    for (int c = 0; c < 2; ++c)
        #pragma unroll
        for (int wi = 0; wi < 4; ++wi) acc[c][wi] = 0.f;

    #pragma unroll
    for (int u = 0; u < 7; ++u) {
        const int row = h + 2 * u - 6;
        if ((unsigned)row >= 64u) continue;
        float xr[2][20];                  // floats w0-8 .. w0+11 per channel
        #pragma unroll
        for (int c = 0; c < 2; ++c) {
            const float4* rp = (const float4*)(xb + (size_t)c * 4096 + row * 64);
            #pragma unroll
            for (int j = 0; j < 5; ++j) {
                const int i4 = wp - 2 + j;
                float4 g = make_float4(0.f, 0.f, 0.f, 0.f);
                if ((unsigned)i4 < 16u) g = rp[i4];
                xr[c][4 * j + 0] = g.x; xr[c][4 * j + 1] = g.y;
                xr[c][4 * j + 2] = g.z; xr[c][4 * j + 3] = g.w;
            }
        }
        #pragma unroll
        for (int v = 0; v < 7; ++v) {
            const float4 a4 = *(const float4*)&as[(u * 7 + v) * 64 + w0];
            const float av[4] = {a4.x, a4.y, a4.z, a4.w};
            #pragma unroll
            for (int wi = 0; wi < 4; ++wi)
                #pragma unroll
                for (int c = 0; c < 2; ++c)
                    acc[c][wi] += av[wi] * xr[c][wi + 2 * v + 2];
        }
    }

    #pragma unroll
    for (int c = 0; c < 2; ++c) {
        float4 st = make_float4(acc[c][0], acc[c][1], acc[c][2], acc[c][3]);
        *(float4*)&out[(size_t)(b * CIN + c0 + c) * 4096 + h * 64 + w0] = st;
    }
}

// ---------------------------------------------------------------------------
// ws: w1t bf16 3,211,264 B | P bf16 [4][4][128][4096] = 16,777,216 B |
//     attn fp32 3,211,264 B   (~23 MB total)
// ---------------------------------------------------------------------------
extern "C" void kernel_launch(void* const* d_in, const int* in_sizes, int n_in,
                              void* d_out, int out_size, void* d_ws, size_t ws_size,
                              hipStream_t stream) {
    const float* x  = (const float*)d_in[0];
    const float* w1 = (const float*)d_in[1];
    const float* b1 = (const float*)d_in[2];
    const float* w2 = (const float*)d_in[3];
    const float* b2 = (const float*)d_in[4];
    float* out = (float*)d_out;

    unsigned short* w1t = (unsigned short*)d_ws;
    unsigned short* P   = (unsigned short*)((char*)d_ws + 3211264);
    float* attn         = (float*)((char*)d_ws + 3211264 + 16777216);

    wtrans_kernel<<<128, 256, 0, stream>>>(w1, w1t);
    conv1_mfma_kernel<<<dim3(KZ, 32, 4), 256, 0, stream>>>(x, w1t, P);
    conv2_softmax_kernel<<<dim3(HW, 4), 512, 0, stream>>>(P, w2, b2, b1, attn);
    gather_kernel<<<dim3(8, HW, 4), 256, 0, stream>>>(x, attn, out);
}